// Round 15
// baseline (110.874 us; speedup 1.0000x reference)
//
#include <hip/hip_runtime.h>
#include <hip/hip_bf16.h>

#define CH   128
#define HH   64
#define WW   64
#define OFFC 18

typedef __attribute__((ext_vector_type(8))) short bf16x8;
typedef __attribute__((ext_vector_type(4))) short bf16x4;
typedef __attribute__((ext_vector_type(4))) float f32x4;

static __device__ __forceinline__ unsigned short f2bf(float f) {
    __hip_bfloat16 h = __float2bfloat16(f);
    return *reinterpret_cast<unsigned short*>(&h);
}
static __device__ __forceinline__ float bf2f(unsigned short u) {
    union { unsigned int i; float f; } x; x.i = ((unsigned int)u) << 16;
    return x.f;
}
// packed f32 helpers (CDNA full-rate VOP3P; numerics identical to scalar)
static __device__ __forceinline__ float2 pk_mul2(float2 a, float2 b) {
    float2 d;
    asm("v_pk_mul_f32 %0, %1, %2" : "=v"(d) : "v"(a), "v"(b));
    return d;
}
static __device__ __forceinline__ float2 pk_fma2(float2 a, float2 b, float2 c) {
    float2 d;
    asm("v_pk_fma_f32 %0, %1, %2, %3" : "=v"(d) : "v"(a), "v"(b), "v"(c));
    return d;
}
static __device__ __forceinline__ float2 bf2f2(unsigned int d) {
    float2 u;
    u.x = __uint_as_float(d << 16);
    u.y = __uint_as_float(d & 0xffff0000u);
    return u;
}

// ---------------------------------------------------------------------------
// Prep: pack weights + NCHW->NHWC (unchanged).
// ---------------------------------------------------------------------------
__global__ __launch_bounds__(256) void prep_kernel(
    const float* __restrict__ x, unsigned short* __restrict__ xh,
    const float* __restrict__ wdc1, const float* __restrict__ wdc2,
    const float* __restrict__ wof1, const float* __restrict__ wof2,
    unsigned short* __restrict__ wpk1, unsigned short* __restrict__ wpk2,
    unsigned short* __restrict__ wpo1, unsigned short* __restrict__ wpo2)
{
    __shared__ float s[CH][WW + 1];
    int blk = blockIdx.x;
    int tid = threadIdx.x;

    if (blk < 1152) {
        const float* w = (blk < 576) ? wdc1 : wdc2;
        unsigned short* wp = (blk < 576) ? wpk1 : wpk2;
        int id = (blk % 576) * 256 + tid;          // 0..147455
        int j    = id & 7;
        int lane = (id >> 3) & 63;
        int ot   = (id >> 9) & 7;
        int kk   = (id >> 12) & 3;
        int k    = id >> 14;
        int o = ot * 16 + (lane & 15);
        int i = kk * 32 + (lane >> 4) * 8 + j;
        wp[id] = f2bf(w[(o * CH + i) * 9 + k]);
        return;
    }
    if (blk < 1440) {
        const float* w = (blk < 1296) ? wof1 : wof2;
        unsigned short* wp = (blk < 1296) ? wpo1 : wpo2;
        int id = ((blk - 1152) % 144) * 256 + tid; // 0..36863
        int j    = id & 7;
        int lane = (id >> 3) & 63;
        int mt   = (id >> 9) & 1;
        int kk   = (id >> 10) & 3;
        int k    = id >> 12;
        int o = mt * 16 + (lane & 15);
        int i = kk * 32 + (lane >> 4) * 8 + j;
        wp[id] = (o < OFFC) ? f2bf(w[(o * CH + i) * 9 + k]) : (unsigned short)0;
        return;
    }

    int nb = blk - 1440;                     // b*64 + h
    const float* xb = x + ((size_t)(nb >> 6) * CH * HH + (nb & 63)) * WW;

    int c_off = tid >> 4, w0 = (tid & 15) * 4;
    #pragma unroll
    for (int it = 0; it < 8; ++it) {
        int c = it * 16 + c_off;
        float4 vv = *(const float4*)&xb[(size_t)c * HH * WW + w0];
        s[c][w0] = vv.x; s[c][w0 + 1] = vv.y; s[c][w0 + 2] = vv.z; s[c][w0 + 3] = vv.w;
    }
    __syncthreads();

    int w = tid & 63, c0 = (tid >> 6) * 32;
    unsigned short* dst = xh + ((size_t)nb * WW + w) * CH + c0;
    unsigned short tmp[32];
    #pragma unroll
    for (int j = 0; j < 32; ++j) tmp[j] = f2bf(s[c0 + j][w]);
    #pragma unroll
    for (int q = 0; q < 4; ++q)
        *(bf16x8*)(dst + q * 8) = *(const bf16x8*)(tmp + q * 8);
}

// ---------------------------------------------------------------------------
// Offset conv via MFMA implicit GEMM (unchanged).
// ---------------------------------------------------------------------------
__global__ __launch_bounds__(256) void off_conv_mfma_kernel(
    const unsigned short* __restrict__ xh,
    const unsigned short* __restrict__ wpo,
    const float* __restrict__ bias,
    unsigned short* __restrict__ offh)
{
    int wgid = blockIdx.x;                   // 512
    int blk  = (wgid & 7) * 64 + (wgid >> 3);
    int b = blk >> 6, oh = blk & 63;
    int tid = threadIdx.x;
    int lane = tid & 63;
    int nt = tid >> 6;
    int nl = lane & 15;
    int kg = lane >> 4;

    f32x4 acc0 = {0.f, 0.f, 0.f, 0.f}, acc1 = {0.f, 0.f, 0.f, 0.f};
    const unsigned short* xb = xh + (size_t)b * HH * WW * CH;

    for (int k = 0; k < 9; ++k) {
        int ky = k / 3, kx = k - ky * 3;
        int ih = oh - 1 + ky;
        if (ih < 0 || ih >= HH) continue;
        int iw = nt * 16 + nl + kx - 1;
        bool valid = (iw >= 0) && (iw < WW);
        const unsigned short* row = xb + ((size_t)ih * WW + (valid ? iw : 0)) * CH + kg * 8;
        const unsigned short* wk = wpo + (size_t)k * 4096;
        #pragma unroll
        for (int kk = 0; kk < 4; ++kk) {
            bf16x8 bfrag = {0, 0, 0, 0, 0, 0, 0, 0};
            if (valid) bfrag = *(const bf16x8*)(row + kk * 32);
            bf16x8 a0 = *(const bf16x8*)(wk + (kk * 2 + 0) * 512 + lane * 8);
            bf16x8 a1 = *(const bf16x8*)(wk + (kk * 2 + 1) * 512 + lane * 8);
            acc0 = __builtin_amdgcn_mfma_f32_16x16x32_bf16(a0, bfrag, acc0, 0, 0, 0);
            acc1 = __builtin_amdgcn_mfma_f32_16x16x32_bf16(a1, bfrag, acc1, 0, 0, 0);
        }
    }

    int ow = nt * 16 + nl;
    #pragma unroll
    for (int r = 0; r < 4; ++r) {
        int co = kg * 4 + r;
        offh[(((size_t)b * OFFC + co) * HH + oh) * WW + ow] = f2bf(acc0[r] + bias[co]);
    }
    if (kg == 0) {
        #pragma unroll
        for (int r = 0; r < 2; ++r) {
            int co = 16 + r;
            offh[(((size_t)b * OFFC + co) * HH + oh) * WW + ow] = f2bf(acc1[r] + bias[co]);
        }
    }
}

// ---------------------------------------------------------------------------
// Deformable conv — PRODUCER/CONSUMER, SMALL-BLOCK edition.
// 256 threads = 2 producer + 2 consumer waves over a 32-ow half-row;
// grid 1024 -> 4 independent P/C pipelines per CU (vs 2 in r12) at the same
// 16 waves/CU. Handoff stalls of one pipeline are covered by the other three.
// Producer thread: (s_ow = tid>>2 in 0..31, cq = tid&3 -> 32-ci slice):
// 16 gather loads (prefetched one tap deep), packed-f32 blend, 4 swizzled
// ds_write_b128. Consumer wave cwi owns o-tiles {4cwi..4cwi+3}: per tap
// 8 ds_read + 16 inline A-loads + 32 MFMA under setprio(1).
// ---------------------------------------------------------------------------
#define P_COORD(K) do {                                                       \
    int k_ = (K);                                                             \
    int ky_ = k_ / 3, kx_ = k_ - ky_ * 3;                                     \
    float dy_ = off_s[2 * k_][s_ow];                                          \
    float dx_ = off_s[2 * k_ + 1][s_ow];                                      \
    float ys_ = (float)(oh - 2 + ky_ * 2) + dy_;                              \
    float xs_ = (float)(ow_g - 2 + kx_ * 2) + dx_;                            \
    float y0f_ = floorf(ys_), x0f_ = floorf(xs_);                             \
    float fy_ = ys_ - y0f_, fx_ = xs_ - x0f_;                                 \
    int y0_ = (int)y0f_, x0_ = (int)x0f_;                                     \
    int y1_ = y0_ + 1, x1_ = x0_ + 1;                                         \
    bool vy0_ = (y0_ >= 0) & (y0_ < HH), vy1_ = (y1_ >= 0) & (y1_ < HH);      \
    bool vx0_ = (x0_ >= 0) & (x0_ < WW), vx1_ = (x1_ >= 0) & (x1_ < WW);      \
    int y0c_ = min(max(y0_, 0), HH - 1), y1c_ = min(max(y1_, 0), HH - 1);     \
    int x0c_ = min(max(x0_, 0), WW - 1), x1c_ = min(max(x1_, 0), WW - 1);     \
    cw[0] = (1.f - fy_) * (1.f - fx_) * ((vy0_ && vx0_) ? 1.f : 0.f);         \
    cw[1] = (1.f - fy_) * fx_         * ((vy0_ && vx1_) ? 1.f : 0.f);         \
    cw[2] = fy_ * (1.f - fx_)         * ((vy1_ && vx0_) ? 1.f : 0.f);         \
    cw[3] = fy_ * fx_                 * ((vy1_ && vx1_) ? 1.f : 0.f);         \
    pt[0] = xb + ((size_t)(y0c_ * WW + x0c_)) * CH + ci0;                     \
    pt[1] = xb + ((size_t)(y0c_ * WW + x1c_)) * CH + ci0;                     \
    pt[2] = xb + ((size_t)(y1c_ * WW + x0c_)) * CH + ci0;                     \
    pt[3] = xb + ((size_t)(y1c_ * WW + x1c_)) * CH + ci0;                     \
} while (0)

#define P_ISSUE() do {                                                        \
    _Pragma("unroll")                                                         \
    for (int c_ = 0; c_ < 4; ++c_) {                                          \
        _Pragma("unroll")                                                     \
        for (int h_ = 0; h_ < 4; ++h_)                                        \
            ld[c_][h_] = *(const bf16x8*)(pt[c_] + h_ * 8);                   \
    }                                                                         \
} while (0)

#define P_BLEND(BUF) do {                                                     \
    int swz_ = (s_ow & 7) << 4;                                               \
    float2 c0p_ = make_float2(cw[0], cw[0]);                                  \
    float2 c1p_ = make_float2(cw[1], cw[1]);                                  \
    float2 c2p_ = make_float2(cw[2], cw[2]);                                  \
    float2 c3p_ = make_float2(cw[3], cw[3]);                                  \
    _Pragma("unroll")                                                         \
    for (int h_ = 0; h_ < 4; ++h_) {                                          \
        const unsigned int* d0_ = (const unsigned int*)&ld[0][h_];            \
        const unsigned int* d1_ = (const unsigned int*)&ld[1][h_];            \
        const unsigned int* d2_ = (const unsigned int*)&ld[2][h_];            \
        const unsigned int* d3_ = (const unsigned int*)&ld[3][h_];            \
        union { bf16x8 v8; unsigned short u[8]; } wu_;                        \
        _Pragma("unroll")                                                     \
        for (int p_ = 0; p_ < 4; ++p_) {                                      \
            float2 r_ = pk_mul2(c0p_, bf2f2(d0_[p_]));                        \
            r_ = pk_fma2(c1p_, bf2f2(d1_[p_]), r_);                           \
            r_ = pk_fma2(c2p_, bf2f2(d2_[p_]), r_);                           \
            r_ = pk_fma2(c3p_, bf2f2(d3_[p_]), r_);                           \
            wu_.u[2 * p_]     = f2bf(r_.x);                                   \
            wu_.u[2 * p_ + 1] = f2bf(r_.y);                                   \
        }                                                                     \
        int byte_ = (s_ow * 256 + ci0 * 2 + h_ * 16) ^ swz_;                  \
        *(bf16x8*)((char*)sB[BUF] + byte_) = wu_.v8;                          \
    }                                                                         \
} while (0)

__global__ __launch_bounds__(256, 4) void deform_pc_kernel(
    const unsigned short* __restrict__ xh,    // (B,64,64,128) bf16 (sampled)
    const unsigned short* __restrict__ offh,  // (B,18,64,64) bf16
    const unsigned short* __restrict__ wpk,   // packed A frags [9][4kk][8ot][512]
    const float* __restrict__ g, const float* __restrict__ beta,
    const float* __restrict__ m, const float* __restrict__ v,
    const float* __restrict__ residual,       // layer2 only
    unsigned short* __restrict__ out_h,       // layer1: NHWC bf16 out
    float* __restrict__ out_f)                // layer2: NCHW f32 out
{
    __shared__ unsigned short sB[2][32 * 128]; // 16 KB ring [buf][ow][ci] swz
    __shared__ float off_s[OFFC][32];          // 2.25 KB offsets (f32)
    __shared__ int flg[4];                     // [0,1]=prod_cnt [2,3]=cons_cnt

    int wgid = blockIdx.x;                    // 1024
    int blk  = (wgid & 7) * 128 + (wgid >> 3);// XCD n owns batch n
    int owh = blk & 1, oh = (blk >> 1) & 63, b = blk >> 7;
    int ow0 = owh * 32;
    int tid = threadIdx.x, lane = tid & 63, wv = tid >> 6;

    const unsigned short* xb = xh + (size_t)b * HH * WW * CH;

    // stage offsets + init flags, single barrier (before any loop loads)
    for (int i = tid; i < OFFC * 32; i += 256) {
        int co = i >> 5, owl = i & 31;
        off_s[co][owl] =
            bf2f(offh[(((size_t)b * OFFC + co) * HH + oh) * WW + ow0 + owl]);
    }
    if (tid < 4) flg[tid] = 0;
    __syncthreads();

    if (wv < 2) {
        // =================== PRODUCER (2 waves) ===========================
        int s_ow = tid >> 2;                  // 0..31
        int cq   = tid & 3;
        int ci0  = cq * 32;                   // 32-ci slice
        int ow_g = ow0 + s_ow;

        float cw[4];
        const unsigned short* pt[4];
        bf16x8 ld[4][4];

        P_COORD(0); P_ISSUE();                // tap-0 gathers in flight

        for (int k = 0; k < 9; ++k) {
            int buf = k & 1;
            if (k >= 2) {
                int tgt = 2 * (k >> 1);       // consumers done with tap k-2
                while (__hip_atomic_load(&flg[2 + buf], __ATOMIC_ACQUIRE,
                                         __HIP_MEMORY_SCOPE_WORKGROUP) < tgt)
                    __builtin_amdgcn_s_sleep(1);
            }
            P_BLEND(buf);                     // waits vmcnt on tap-k loads only
            asm volatile("s_waitcnt lgkmcnt(0)" ::: "memory");
            if (lane == 0)
                __hip_atomic_fetch_add(&flg[buf], 1, __ATOMIC_RELEASE,
                                       __HIP_MEMORY_SCOPE_WORKGROUP);
            if (k < 8) { P_COORD(k + 1); P_ISSUE(); }  // fly through next spin
        }
    } else {
        // =================== CONSUMER (2 waves) ===========================
        int cwi = wv - 2;                     // 0..1: o-tiles {4cwi..4cwi+3}
        f32x4 acc[4][2];                      // [otl][owt]
        #pragma unroll
        for (int a = 0; a < 4; ++a)
            #pragma unroll
            for (int q = 0; q < 2; ++q) acc[a][q] = (f32x4){0.f, 0.f, 0.f, 0.f};

        for (int k = 0; k < 9; ++k) {
            int buf = k & 1;
            int tgt = 2 * ((k >> 1) + 1);     // producers done with tap k
            while (__hip_atomic_load(&flg[buf], __ATOMIC_ACQUIRE,
                                     __HIP_MEMORY_SCOPE_WORKGROUP) < tgt)
                __builtin_amdgcn_s_sleep(1);

            const unsigned short* wk = wpk + (size_t)k * 16384;
            __builtin_amdgcn_s_setprio(1);
            #pragma unroll
            for (int kk = 0; kk < 4; ++kk) {
                bf16x8 bf0, bf1;
                {
                    int owl0 = (lane & 15);
                    int owl1 = 16 + (lane & 15);
                    int rb0 = (owl0 * 256 + (kk * 32 + (lane >> 4) * 8) * 2)
                              ^ ((owl0 & 7) << 4);
                    int rb1 = (owl1 * 256 + (kk * 32 + (lane >> 4) * 8) * 2)
                              ^ ((owl1 & 7) << 4);
                    bf0 = *(const bf16x8*)((const char*)sB[buf] + rb0);
                    bf1 = *(const bf16x8*)((const char*)sB[buf] + rb1);
                }
                #pragma unroll
                for (int otl = 0; otl < 4; ++otl) {
                    bf16x8 a = *(const bf16x8*)(
                        wk + (size_t)(kk * 8 + 4 * cwi + otl) * 512 + lane * 8);
                    acc[otl][0] = __builtin_amdgcn_mfma_f32_16x16x32_bf16(
                                      a, bf0, acc[otl][0], 0, 0, 0);
                    acc[otl][1] = __builtin_amdgcn_mfma_f32_16x16x32_bf16(
                                      a, bf1, acc[otl][1], 0, 0, 0);
                }
            }
            __builtin_amdgcn_s_setprio(0);
            asm volatile("s_waitcnt lgkmcnt(0)" ::: "memory");
            if (lane == 0)
                __hip_atomic_fetch_add(&flg[2 + buf], 1, __ATOMIC_RELEASE,
                                       __HIP_MEMORY_SCOPE_WORKGROUP);
        }

        // ---- epilogue (2 consumer waves cover all 128 o) ---------------
        #pragma unroll
        for (int otl = 0; otl < 4; ++otl) {
            int ob = (4 * cwi + otl) * 16 + (lane >> 4) * 4;
            float inv[4], sh[4];
            #pragma unroll
            for (int r = 0; r < 4; ++r) {
                int o = ob + r;
                float iv = g[o] / sqrtf(v[o] + 1e-5f);
                inv[r] = iv; sh[r] = beta[o] - m[o] * iv;
            }
            if (out_h != nullptr) {
                #pragma unroll
                for (int owt = 0; owt < 2; ++owt) {
                    int ow = ow0 + owt * 16 + (lane & 15);
                    union { bf16x4 v4; unsigned short u[4]; } pk;
                    #pragma unroll
                    for (int r = 0; r < 4; ++r) {
                        float val = acc[otl][owt][r] * inv[r] + sh[r];
                        pk.u[r] = f2bf(fmaxf(val, 0.f));
                    }
                    *(bf16x4*)(out_h + ((size_t)(b * HH + oh) * WW + ow) * CH + ob) = pk.v4;
                }
            } else {
                #pragma unroll
                for (int r = 0; r < 4; ++r) {
                    int o = ob + r;
                    #pragma unroll
                    for (int owt = 0; owt < 2; ++owt) {
                        int ow = ow0 + owt * 16 + (lane & 15);
                        size_t idx = (((size_t)b * CH + o) * HH + oh) * WW + ow;
                        float val = acc[otl][owt][r] * inv[r] + sh[r] + residual[idx];
                        out_f[idx] = fmaxf(val, 0.f);
                    }
                }
            }
        }
    }
}

// ---------------------------------------------------------------------------
extern "C" void kernel_launch(void* const* d_in, const int* in_sizes, int n_in,
                              void* d_out, int out_size, void* d_ws, size_t ws_size,
                              hipStream_t stream)
{
    const float* x      = (const float*)d_in[0];
    const float* w_off1 = (const float*)d_in[1];
    const float* b_off1 = (const float*)d_in[2];
    const float* w_dc1  = (const float*)d_in[3];
    const float* g1     = (const float*)d_in[4];
    const float* beta1  = (const float*)d_in[5];
    const float* m1     = (const float*)d_in[6];
    const float* v1     = (const float*)d_in[7];
    const float* w_off2 = (const float*)d_in[8];
    const float* b_off2 = (const float*)d_in[9];
    const float* w_dc2  = (const float*)d_in[10];
    const float* g2     = (const float*)d_in[11];
    const float* beta2  = (const float*)d_in[12];
    const float* m2     = (const float*)d_in[13];
    const float* v2     = (const float*)d_in[14];
    float* out = (float*)d_out;

    char* ws = (char*)d_ws;
    unsigned short* xh    = (unsigned short*)ws;                  // 8,388,608 B
    unsigned short* out1h = (unsigned short*)(ws + 8388608);      // 8,388,608 B
    unsigned short* offh  = (unsigned short*)(ws + 16777216);     // 1,179,648 B
    unsigned short* wpk1  = (unsigned short*)(ws + 17956864);     //   294,912 B
    unsigned short* wpk2  = (unsigned short*)(ws + 18251776);     //   294,912 B
    unsigned short* wpo1  = (unsigned short*)(ws + 18546688);     //    73,728 B
    unsigned short* wpo2  = (unsigned short*)(ws + 18620416);     //    73,728 B

    prep_kernel<<<1952, 256, 0, stream>>>(x, xh, w_dc1, w_dc2, w_off1, w_off2,
                                          wpk1, wpk2, wpo1, wpo2);

    // Layer 1
    off_conv_mfma_kernel<<<512, 256, 0, stream>>>(xh, wpo1, b_off1, offh);
    deform_pc_kernel<<<1024, 256, 0, stream>>>(xh, offh, wpk1,
                                               g1, beta1, m1, v1,
                                               nullptr, out1h, nullptr);
    // Layer 2
    off_conv_mfma_kernel<<<512, 256, 0, stream>>>(out1h, wpo2, b_off2, offh);
    deform_pc_kernel<<<1024, 256, 0, stream>>>(out1h, offh, wpk2,
                                               g2, beta2, m2, v2,
                                               x, nullptr, out);
}

// Round 16
// 103.879 us; speedup vs baseline: 1.0673x; 1.0673x over previous
//
#include <hip/hip_runtime.h>
#include <hip/hip_bf16.h>

#define CH   128
#define HH   64
#define WW   64
#define OFFC 18

typedef __attribute__((ext_vector_type(8))) short bf16x8;
typedef __attribute__((ext_vector_type(4))) short bf16x4;
typedef __attribute__((ext_vector_type(4))) float f32x4;

static __device__ __forceinline__ unsigned short f2bf(float f) {
    __hip_bfloat16 h = __float2bfloat16(f);
    return *reinterpret_cast<unsigned short*>(&h);
}
static __device__ __forceinline__ float bf2f(unsigned short u) {
    union { unsigned int i; float f; } x; x.i = ((unsigned int)u) << 16;
    return x.f;
}
// packed f32 helpers (CDNA full-rate VOP3P; numerics identical to scalar)
static __device__ __forceinline__ float2 pk_mul2(float2 a, float2 b) {
    float2 d;
    asm("v_pk_mul_f32 %0, %1, %2" : "=v"(d) : "v"(a), "v"(b));
    return d;
}
static __device__ __forceinline__ float2 pk_fma2(float2 a, float2 b, float2 c) {
    float2 d;
    asm("v_pk_fma_f32 %0, %1, %2, %3" : "=v"(d) : "v"(a), "v"(b), "v"(c));
    return d;
}
static __device__ __forceinline__ float2 bf2f2(unsigned int d) {
    float2 u;
    u.x = __uint_as_float(d << 16);
    u.y = __uint_as_float(d & 0xffff0000u);
    return u;
}

// ---------------------------------------------------------------------------
// Prep: pack weights + NCHW->NHWC.  NHWC store remapped: thread = (pixel,
// c-quarter) so each wave's 4 stores fill a contiguous 4KB span (old layout
// scattered 16B/lane at 256B stride across 16KB -> 64 lines per store inst).
// ---------------------------------------------------------------------------
__global__ __launch_bounds__(256) void prep_kernel(
    const float* __restrict__ x, unsigned short* __restrict__ xh,
    const float* __restrict__ wdc1, const float* __restrict__ wdc2,
    const float* __restrict__ wof1, const float* __restrict__ wof2,
    unsigned short* __restrict__ wpk1, unsigned short* __restrict__ wpk2,
    unsigned short* __restrict__ wpo1, unsigned short* __restrict__ wpo2)
{
    __shared__ float s[CH][WW + 1];
    int blk = blockIdx.x;
    int tid = threadIdx.x;

    if (blk < 1152) {
        const float* w = (blk < 576) ? wdc1 : wdc2;
        unsigned short* wp = (blk < 576) ? wpk1 : wpk2;
        int id = (blk % 576) * 256 + tid;          // 0..147455
        int j    = id & 7;
        int lane = (id >> 3) & 63;
        int ot   = (id >> 9) & 7;
        int kk   = (id >> 12) & 3;
        int k    = id >> 14;
        int o = ot * 16 + (lane & 15);
        int i = kk * 32 + (lane >> 4) * 8 + j;
        wp[id] = f2bf(w[(o * CH + i) * 9 + k]);
        return;
    }
    if (blk < 1440) {
        const float* w = (blk < 1296) ? wof1 : wof2;
        unsigned short* wp = (blk < 1296) ? wpo1 : wpo2;
        int id = ((blk - 1152) % 144) * 256 + tid; // 0..36863
        int j    = id & 7;
        int lane = (id >> 3) & 63;
        int mt   = (id >> 9) & 1;
        int kk   = (id >> 10) & 3;
        int k    = id >> 12;
        int o = mt * 16 + (lane & 15);
        int i = kk * 32 + (lane >> 4) * 8 + j;
        wp[id] = (o < OFFC) ? f2bf(w[(o * CH + i) * 9 + k]) : (unsigned short)0;
        return;
    }

    int nb = blk - 1440;                     // b*64 + h
    const float* xb = x + ((size_t)(nb >> 6) * CH * HH + (nb & 63)) * WW;

    int c_off = tid >> 4, w0 = (tid & 15) * 4;
    #pragma unroll
    for (int it = 0; it < 8; ++it) {
        int c = it * 16 + c_off;
        float4 vv = *(const float4*)&xb[(size_t)c * HH * WW + w0];
        s[c][w0] = vv.x; s[c][w0 + 1] = vv.y; s[c][w0 + 2] = vv.z; s[c][w0 + 3] = vv.w;
    }
    __syncthreads();

    int w4 = tid >> 2, c0 = (tid & 3) * 32;  // pixel, channel-quarter
    unsigned short* dst = xh + ((size_t)nb * WW + w4) * CH + c0;
    unsigned short tmp[32];
    #pragma unroll
    for (int j = 0; j < 32; ++j) tmp[j] = f2bf(s[c0 + j][w4]);
    #pragma unroll
    for (int q = 0; q < 4; ++q)
        *(bf16x8*)(dst + q * 8) = *(const bf16x8*)(tmp + q * 8);
}

// ---------------------------------------------------------------------------
// Offset conv via MFMA implicit GEMM — 8-wave edition.
// 512 blocks x 512 thr: wave = (mt co-half, nt ow-tile); 4 MFMA/tap/wave.
// Doubles waves/SIMD (2 -> 4) for the latency-chained tap loop; A-frags are
// wave-uniform (L1 broadcast, shared across nt waves). Regular 9-tap loop
// (clamped addr + zeroed frag instead of skip) keeps the pipeline uniform.
// ---------------------------------------------------------------------------
__global__ __launch_bounds__(512) void off_conv_mfma_kernel(
    const unsigned short* __restrict__ xh,
    const unsigned short* __restrict__ wpo,
    const float* __restrict__ bias,
    unsigned short* __restrict__ offh)
{
    int wgid = blockIdx.x;                   // 512
    int blk  = (wgid & 7) * 64 + (wgid >> 3);
    int b = blk >> 6, oh = blk & 63;
    int tid = threadIdx.x;
    int lane = tid & 63;
    int wv = tid >> 6;
    int mt = wv >> 2;                        // co half (0: co0-15, 1: co16-31)
    int nt = wv & 3;                         // ow tile
    int nl = lane & 15;
    int kg = lane >> 4;

    f32x4 acc = {0.f, 0.f, 0.f, 0.f};
    const unsigned short* xb = xh + (size_t)b * HH * WW * CH;

    #pragma unroll
    for (int k = 0; k < 9; ++k) {
        int ky = k / 3, kx = k - ky * 3;
        int ih = oh - 1 + ky;
        int iw = nt * 16 + nl + kx - 1;
        bool valid = (ih >= 0) && (ih < HH) && (iw >= 0) && (iw < WW);
        int ihc = min(max(ih, 0), HH - 1);
        int iwc = min(max(iw, 0), WW - 1);
        const unsigned short* row = xb + ((size_t)ihc * WW + iwc) * CH + kg * 8;
        const unsigned short* wk = wpo + (size_t)k * 4096;
        #pragma unroll
        for (int kk = 0; kk < 4; ++kk) {
            bf16x8 bfrag = {0, 0, 0, 0, 0, 0, 0, 0};
            if (valid) bfrag = *(const bf16x8*)(row + kk * 32);
            bf16x8 a = *(const bf16x8*)(wk + (kk * 2 + mt) * 512 + lane * 8);
            acc = __builtin_amdgcn_mfma_f32_16x16x32_bf16(a, bfrag, acc, 0, 0, 0);
        }
    }

    int ow = nt * 16 + nl;
    if (mt == 0) {
        #pragma unroll
        for (int r = 0; r < 4; ++r) {
            int co = kg * 4 + r;             // 0..15
            offh[(((size_t)b * OFFC + co) * HH + oh) * WW + ow] = f2bf(acc[r] + bias[co]);
        }
    } else if (kg == 0) {
        #pragma unroll
        for (int r = 0; r < 2; ++r) {
            int co = 16 + r;                 // 16,17
            offh[(((size_t)b * OFFC + co) * HH + oh) * WW + ow] = f2bf(acc[r] + bias[co]);
        }
    }
}

// ---------------------------------------------------------------------------
// Deformable conv — PRODUCER/CONSUMER with DEEP PREFETCH (r12/r14 structure,
// the best measured: 90.6-90.9 µs total). Unchanged this round.
// ---------------------------------------------------------------------------
#define P_COORD(K, OW, CW, PTR) do {                                          \
    int ky_ = (K) / 3, kx_ = (K) - ky_ * 3;                                   \
    float dy_ = off_s[2 * (K)][OW];                                           \
    float dx_ = off_s[2 * (K) + 1][OW];                                       \
    float ys_ = (float)(oh - 2 + ky_ * 2) + dy_;                              \
    float xs_ = (float)((OW) - 2 + kx_ * 2) + dx_;                            \
    float y0f_ = floorf(ys_), x0f_ = floorf(xs_);                             \
    float fy_ = ys_ - y0f_, fx_ = xs_ - x0f_;                                 \
    int y0_ = (int)y0f_, x0_ = (int)x0f_;                                     \
    int y1_ = y0_ + 1, x1_ = x0_ + 1;                                         \
    bool vy0_ = (y0_ >= 0) & (y0_ < HH), vy1_ = (y1_ >= 0) & (y1_ < HH);      \
    bool vx0_ = (x0_ >= 0) & (x0_ < WW), vx1_ = (x1_ >= 0) & (x1_ < WW);      \
    int y0c_ = min(max(y0_, 0), HH - 1), y1c_ = min(max(y1_, 0), HH - 1);     \
    int x0c_ = min(max(x0_, 0), WW - 1), x1c_ = min(max(x1_, 0), WW - 1);     \
    CW[0] = (1.f - fy_) * (1.f - fx_) * ((vy0_ && vx0_) ? 1.f : 0.f);         \
    CW[1] = (1.f - fy_) * fx_         * ((vy0_ && vx1_) ? 1.f : 0.f);         \
    CW[2] = fy_ * (1.f - fx_)         * ((vy1_ && vx0_) ? 1.f : 0.f);         \
    CW[3] = fy_ * fx_                 * ((vy1_ && vx1_) ? 1.f : 0.f);         \
    PTR[0] = xb + ((size_t)(y0c_ * WW + x0c_)) * CH + cig * 8;                \
    PTR[1] = xb + ((size_t)(y0c_ * WW + x1c_)) * CH + cig * 8;                \
    PTR[2] = xb + ((size_t)(y1c_ * WW + x0c_)) * CH + cig * 8;                \
    PTR[3] = xb + ((size_t)(y1c_ * WW + x1c_)) * CH + cig * 8;                \
} while (0)

#define P_ISSUE(PTR, LD) do {                                                 \
    _Pragma("unroll")                                                         \
    for (int c_ = 0; c_ < 4; ++c_) {                                          \
        LD[0][c_] = *(const bf16x8*)(PTR[c_]);                                \
        LD[1][c_] = *(const bf16x8*)(PTR[c_] + 64);                           \
    }                                                                         \
} while (0)

#define P_BLEND(OW, CW, LD, BUF) do {                                         \
    int swz_ = ((OW) & 7) << 4;                                               \
    float2 cw0p_ = make_float2(CW[0], CW[0]);                                 \
    float2 cw1p_ = make_float2(CW[1], CW[1]);                                 \
    float2 cw2p_ = make_float2(CW[2], CW[2]);                                 \
    float2 cw3p_ = make_float2(CW[3], CW[3]);                                 \
    _Pragma("unroll")                                                         \
    for (int q_ = 0; q_ < 2; ++q_) {                                          \
        const unsigned int* d0_ = (const unsigned int*)&LD[q_][0];            \
        const unsigned int* d1_ = (const unsigned int*)&LD[q_][1];            \
        const unsigned int* d2_ = (const unsigned int*)&LD[q_][2];            \
        const unsigned int* d3_ = (const unsigned int*)&LD[q_][3];            \
        union { bf16x8 v8; unsigned short u[8]; } wu_;                        \
        _Pragma("unroll")                                                     \
        for (int p_ = 0; p_ < 4; ++p_) {                                      \
            float2 r_ = pk_mul2(cw0p_, bf2f2(d0_[p_]));                       \
            r_ = pk_fma2(cw1p_, bf2f2(d1_[p_]), r_);                          \
            r_ = pk_fma2(cw2p_, bf2f2(d2_[p_]), r_);                          \
            r_ = pk_fma2(cw3p_, bf2f2(d3_[p_]), r_);                          \
            wu_.u[2 * p_]     = f2bf(r_.x);                                   \
            wu_.u[2 * p_ + 1] = f2bf(r_.y);                                   \
        }                                                                     \
        int byte_ = ((OW) * 256 + (q_ * 64 + cig * 8) * 2) ^ swz_;            \
        *(bf16x8*)((char*)sB[BUF] + byte_) = wu_.v8;                          \
    }                                                                         \
} while (0)

#define C_PREF(K, AP) do {                                                    \
    const unsigned short* wk_ = wpk + (size_t)(K) * 16384;                    \
    _Pragma("unroll")                                                         \
    for (int kk_ = 0; kk_ < 4; ++kk_) {                                       \
        AP[kk_ * 2 + 0] = *(const bf16x8*)(wk_ + (size_t)(kk_ * 8 + 2 * cwi)     * 512 + lane * 8); \
        AP[kk_ * 2 + 1] = *(const bf16x8*)(wk_ + (size_t)(kk_ * 8 + 2 * cwi + 1) * 512 + lane * 8); \
    }                                                                         \
} while (0)

__global__ __launch_bounds__(512, 4) void deform_pc_kernel(
    const unsigned short* __restrict__ xh,    // (B,64,64,128) bf16 (sampled)
    const unsigned short* __restrict__ offh,  // (B,18,64,64) bf16
    const unsigned short* __restrict__ wpk,   // packed A frags [9][4kk][8ot][512]
    const float* __restrict__ g, const float* __restrict__ beta,
    const float* __restrict__ m, const float* __restrict__ v,
    const float* __restrict__ residual,       // layer2 only
    unsigned short* __restrict__ out_h,       // layer1: NHWC bf16 out
    float* __restrict__ out_f)                // layer2: NCHW f32 out
{
    __shared__ unsigned short sB[2][64 * 128]; // 32 KB ring [buf][ow][ci] swz
    __shared__ float off_s[OFFC][WW];          // 4.5 KB offsets (f32)
    __shared__ int flg[4];                     // [0,1]=prod_cnt [2,3]=cons_cnt

    int wgid = blockIdx.x;                    // 512
    int blk  = (wgid & 7) * 64 + (wgid >> 3); // XCD n owns batch n
    int b = blk >> 6, oh = blk & 63;
    int tid = threadIdx.x, lane = tid & 63, wv = tid >> 6;

    const unsigned short* xb = xh + (size_t)b * HH * WW * CH;

    // stage offsets + init flags, single barrier (before any loop loads)
    for (int i = tid; i < OFFC * WW; i += 512) {
        int co = i >> 6, owl = i & 63;
        off_s[co][owl] =
            bf2f(offh[(((size_t)b * OFFC + co) * HH + oh) * WW + owl]);
    }
    if (tid < 4) flg[tid] = 0;
    __syncthreads();

    if (wv < 4) {
        // =================== PRODUCER =====================================
        int s_ow = tid >> 3;                  // 0..31 (also serves +32)
        int cig  = tid & 7;                   // 16B chunk id within pixel

        float cwA[4], cwB[4];
        const unsigned short *ptA[4], *ptB[4];
        bf16x8 ldA[2][4], ldB[2][4];

        P_COORD(0, s_ow, cwA, ptA);
        P_COORD(0, s_ow + 32, cwB, ptB);
        P_ISSUE(ptA, ldA);
        P_ISSUE(ptB, ldB);

        for (int k = 0; k < 9; ++k) {
            int buf = k & 1;
            if (k >= 2) {
                int tgt = 4 * (k >> 1);       // consumers done with tap k-2
                while (__hip_atomic_load(&flg[2 + buf], __ATOMIC_ACQUIRE,
                                         __HIP_MEMORY_SCOPE_WORKGROUP) < tgt)
                    __builtin_amdgcn_s_sleep(1);
            }
            P_BLEND(s_ow,      cwA, ldA, buf);
            P_BLEND(s_ow + 32, cwB, ldB, buf);
            asm volatile("s_waitcnt lgkmcnt(0)" ::: "memory");
            if (lane == 0)
                __hip_atomic_fetch_add(&flg[buf], 1, __ATOMIC_RELEASE,
                                       __HIP_MEMORY_SCOPE_WORKGROUP);
            if (k < 8) {
                P_COORD(k + 1, s_ow, cwA, ptA);
                P_COORD(k + 1, s_ow + 32, cwB, ptB);
                P_ISSUE(ptA, ldA);
                P_ISSUE(ptB, ldB);
            }
        }
    } else {
        // =================== CONSUMER =====================================
        int cwi = wv - 4;                     // 0..3: o-tiles {2cwi, 2cwi+1}
        f32x4 acc[2][4];
        #pragma unroll
        for (int a = 0; a < 2; ++a)
            #pragma unroll
            for (int q = 0; q < 4; ++q) acc[a][q] = (f32x4){0.f, 0.f, 0.f, 0.f};

        bf16x8 aP[8];
        C_PREF(0, aP);                        // A frags for tap 0 in flight

        for (int k = 0; k < 9; ++k) {
            int buf = k & 1;
            int tgt = 4 * ((k >> 1) + 1);     // producers done with tap k
            while (__hip_atomic_load(&flg[buf], __ATOMIC_ACQUIRE,
                                     __HIP_MEMORY_SCOPE_WORKGROUP) < tgt)
                __builtin_amdgcn_s_sleep(1);

            __builtin_amdgcn_s_setprio(1);
            #pragma unroll
            for (int kk = 0; kk < 4; ++kk) {
                #pragma unroll
                for (int owt = 0; owt < 4; ++owt) {
                    int owl = owt * 16 + (lane & 15);
                    int rbyte = (owl * 256 + (kk * 32 + (lane >> 4) * 8) * 2)
                                ^ ((owl & 7) << 4);
                    bf16x8 bfv = *(const bf16x8*)((const char*)sB[buf] + rbyte);
                    acc[0][owt] = __builtin_amdgcn_mfma_f32_16x16x32_bf16(
                                      aP[kk * 2 + 0], bfv, acc[0][owt], 0, 0, 0);
                    acc[1][owt] = __builtin_amdgcn_mfma_f32_16x16x32_bf16(
                                      aP[kk * 2 + 1], bfv, acc[1][owt], 0, 0, 0);
                }
            }
            __builtin_amdgcn_s_setprio(0);
            asm volatile("s_waitcnt lgkmcnt(0)" ::: "memory");
            if (lane == 0)
                __hip_atomic_fetch_add(&flg[2 + buf], 1, __ATOMIC_RELEASE,
                                       __HIP_MEMORY_SCOPE_WORKGROUP);
            if (k < 8) C_PREF(k + 1, aP);
        }

        // ---- epilogue (consumers hold all 128 o across 4 waves) --------
        #pragma unroll
        for (int otl = 0; otl < 2; ++otl) {
            int ob = (2 * cwi + otl) * 16 + (lane >> 4) * 4;
            float inv[4], sh[4];
            #pragma unroll
            for (int r = 0; r < 4; ++r) {
                int o = ob + r;
                float iv = g[o] / sqrtf(v[o] + 1e-5f);
                inv[r] = iv; sh[r] = beta[o] - m[o] * iv;
            }
            if (out_h != nullptr) {
                #pragma unroll
                for (int owt = 0; owt < 4; ++owt) {
                    int ow = owt * 16 + (lane & 15);
                    union { bf16x4 v4; unsigned short u[4]; } pk;
                    #pragma unroll
                    for (int r = 0; r < 4; ++r) {
                        float val = acc[otl][owt][r] * inv[r] + sh[r];
                        pk.u[r] = f2bf(fmaxf(val, 0.f));
                    }
                    *(bf16x4*)(out_h + ((size_t)(b * HH + oh) * WW + ow) * CH + ob) = pk.v4;
                }
            } else {
                #pragma unroll
                for (int r = 0; r < 4; ++r) {
                    int o = ob + r;
                    #pragma unroll
                    for (int owt = 0; owt < 4; ++owt) {
                        int ow = owt * 16 + (lane & 15);
                        size_t idx = (((size_t)b * CH + o) * HH + oh) * WW + ow;
                        float val = acc[otl][owt][r] * inv[r] + sh[r] + residual[idx];
                        out_f[idx] = fmaxf(val, 0.f);
                    }
                }
            }
        }
    }
}

// ---------------------------------------------------------------------------
extern "C" void kernel_launch(void* const* d_in, const int* in_sizes, int n_in,
                              void* d_out, int out_size, void* d_ws, size_t ws_size,
                              hipStream_t stream)
{
    const float* x      = (const float*)d_in[0];
    const float* w_off1 = (const float*)d_in[1];
    const float* b_off1 = (const float*)d_in[2];
    const float* w_dc1  = (const float*)d_in[3];
    const float* g1     = (const float*)d_in[4];
    const float* beta1  = (const float*)d_in[5];
    const float* m1     = (const float*)d_in[6];
    const float* v1     = (const float*)d_in[7];
    const float* w_off2 = (const float*)d_in[8];
    const float* b_off2 = (const float*)d_in[9];
    const float* w_dc2  = (const float*)d_in[10];
    const float* g2     = (const float*)d_in[11];
    const float* beta2  = (const float*)d_in[12];
    const float* m2     = (const float*)d_in[13];
    const float* v2     = (const float*)d_in[14];
    float* out = (float*)d_out;

    char* ws = (char*)d_ws;
    unsigned short* xh    = (unsigned short*)ws;                  // 8,388,608 B
    unsigned short* out1h = (unsigned short*)(ws + 8388608);      // 8,388,608 B
    unsigned short* offh  = (unsigned short*)(ws + 16777216);     // 1,179,648 B
    unsigned short* wpk1  = (unsigned short*)(ws + 17956864);     //   294,912 B
    unsigned short* wpk2  = (unsigned short*)(ws + 18251776);     //   294,912 B
    unsigned short* wpo1  = (unsigned short*)(ws + 18546688);     //    73,728 B
    unsigned short* wpo2  = (unsigned short*)(ws + 18620416);     //    73,728 B

    prep_kernel<<<1952, 256, 0, stream>>>(x, xh, w_dc1, w_dc2, w_off1, w_off2,
                                          wpk1, wpk2, wpo1, wpo2);

    // Layer 1
    off_conv_mfma_kernel<<<512, 512, 0, stream>>>(xh, wpo1, b_off1, offh);
    deform_pc_kernel<<<512, 512, 0, stream>>>(xh, offh, wpk1,
                                              g1, beta1, m1, v1,
                                              nullptr, out1h, nullptr);
    // Layer 2
    off_conv_mfma_kernel<<<512, 512, 0, stream>>>(out1h, wpo2, b_off2, offh);
    deform_pc_kernel<<<512, 512, 0, stream>>>(out1h, offh, wpk2,
                                              g2, beta2, m2, v2,
                                              x, nullptr, out);
}

// Round 17
// 87.712 us; speedup vs baseline: 1.2641x; 1.1843x over previous
//
#include <hip/hip_runtime.h>
#include <hip/hip_bf16.h>

#define CH   128
#define HH   64
#define WW   64
#define OFFC 18

typedef __attribute__((ext_vector_type(8))) short bf16x8;
typedef __attribute__((ext_vector_type(4))) short bf16x4;
typedef __attribute__((ext_vector_type(4))) float f32x4;

static __device__ __forceinline__ unsigned short f2bf(float f) {
    __hip_bfloat16 h = __float2bfloat16(f);
    return *reinterpret_cast<unsigned short*>(&h);
}
static __device__ __forceinline__ float bf2f(unsigned short u) {
    union { unsigned int i; float f; } x; x.i = ((unsigned int)u) << 16;
    return x.f;
}
// packed f32 helpers (CDNA full-rate VOP3P; numerics identical to scalar)
static __device__ __forceinline__ float2 pk_mul2(float2 a, float2 b) {
    float2 d;
    asm("v_pk_mul_f32 %0, %1, %2" : "=v"(d) : "v"(a), "v"(b));
    return d;
}
static __device__ __forceinline__ float2 pk_fma2(float2 a, float2 b, float2 c) {
    float2 d;
    asm("v_pk_fma_f32 %0, %1, %2, %3" : "=v"(d) : "v"(a), "v"(b), "v"(c));
    return d;
}
static __device__ __forceinline__ float2 bf2f2(unsigned int d) {
    float2 u;
    u.x = __uint_as_float(d << 16);
    u.y = __uint_as_float(d & 0xffff0000u);
    return u;
}

// ---------------------------------------------------------------------------
// Prep: pack weights + NCHW->NHWC (r14 layout — r16's remap had a 4-way
// LDS read conflict and was reverted).
// ---------------------------------------------------------------------------
__global__ __launch_bounds__(256) void prep_kernel(
    const float* __restrict__ x, unsigned short* __restrict__ xh,
    const float* __restrict__ wdc1, const float* __restrict__ wdc2,
    const float* __restrict__ wof1, const float* __restrict__ wof2,
    unsigned short* __restrict__ wpk1, unsigned short* __restrict__ wpk2,
    unsigned short* __restrict__ wpo1, unsigned short* __restrict__ wpo2)
{
    __shared__ float s[CH][WW + 1];
    int blk = blockIdx.x;
    int tid = threadIdx.x;

    if (blk < 1152) {
        const float* w = (blk < 576) ? wdc1 : wdc2;
        unsigned short* wp = (blk < 576) ? wpk1 : wpk2;
        int id = (blk % 576) * 256 + tid;          // 0..147455
        int j    = id & 7;
        int lane = (id >> 3) & 63;
        int ot   = (id >> 9) & 7;
        int kk   = (id >> 12) & 3;
        int k    = id >> 14;
        int o = ot * 16 + (lane & 15);
        int i = kk * 32 + (lane >> 4) * 8 + j;
        wp[id] = f2bf(w[(o * CH + i) * 9 + k]);
        return;
    }
    if (blk < 1440) {
        const float* w = (blk < 1296) ? wof1 : wof2;
        unsigned short* wp = (blk < 1296) ? wpo1 : wpo2;
        int id = ((blk - 1152) % 144) * 256 + tid; // 0..36863
        int j    = id & 7;
        int lane = (id >> 3) & 63;
        int mt   = (id >> 9) & 1;
        int kk   = (id >> 10) & 3;
        int k    = id >> 12;
        int o = mt * 16 + (lane & 15);
        int i = kk * 32 + (lane >> 4) * 8 + j;
        wp[id] = (o < OFFC) ? f2bf(w[(o * CH + i) * 9 + k]) : (unsigned short)0;
        return;
    }

    int nb = blk - 1440;                     // b*64 + h
    const float* xb = x + ((size_t)(nb >> 6) * CH * HH + (nb & 63)) * WW;

    int c_off = tid >> 4, w0 = (tid & 15) * 4;
    #pragma unroll
    for (int it = 0; it < 8; ++it) {
        int c = it * 16 + c_off;
        float4 vv = *(const float4*)&xb[(size_t)c * HH * WW + w0];
        s[c][w0] = vv.x; s[c][w0 + 1] = vv.y; s[c][w0 + 2] = vv.z; s[c][w0 + 3] = vv.w;
    }
    __syncthreads();

    int w = tid & 63, c0 = (tid >> 6) * 32;
    unsigned short* dst = xh + ((size_t)nb * WW + w) * CH + c0;
    unsigned short tmp[32];
    #pragma unroll
    for (int j = 0; j < 32; ++j) tmp[j] = f2bf(s[c0 + j][w]);
    #pragma unroll
    for (int q = 0; q < 4; ++q)
        *(bf16x8*)(dst + q * 8) = *(const bf16x8*)(tmp + q * 8);
}

// ---------------------------------------------------------------------------
// Offset conv via MFMA implicit GEMM — DEEP-PREFETCH edition (r12 geometry:
// 512 blocks x 256 thr, wave nt = ow-tile, M=32 in one wave).
// Per tap k: A(k+1) and B(k+1) are issued BEFORE the tap-k MFMA cluster, so
// the wait before MFMA(k) retires only tap-k loads while 12 tap-(k+1) loads
// stay in flight (r6 lesson: A must be prefetched too, else its inline wait
// drains the B prefetch). Fully unrolled two-bank ladder, static indices.
// ---------------------------------------------------------------------------
#define OFF_LOADB(K, BD) do {                                                 \
    int ky_ = (K) / 3, kx_ = (K) - ky_ * 3;                                   \
    int ih_ = oh - 1 + ky_;                                                   \
    int iw_ = nt * 16 + nl + kx_ - 1;                                         \
    bool valid_ = (ih_ >= 0) && (ih_ < HH) && (iw_ >= 0) && (iw_ < WW);       \
    int ihc_ = min(max(ih_, 0), HH - 1);                                      \
    int iwc_ = min(max(iw_, 0), WW - 1);                                      \
    const unsigned short* row_ = xb + ((size_t)ihc_ * WW + iwc_) * CH + kg * 8; \
    _Pragma("unroll")                                                         \
    for (int kk_ = 0; kk_ < 4; ++kk_) {                                       \
        BD[kk_] = (bf16x8){0, 0, 0, 0, 0, 0, 0, 0};                           \
        if (valid_) BD[kk_] = *(const bf16x8*)(row_ + kk_ * 32);              \
    }                                                                         \
} while (0)

#define OFF_LOADA(K, AD) do {                                                 \
    const unsigned short* wk_ = wpo + (size_t)(K) * 4096;                     \
    _Pragma("unroll")                                                         \
    for (int kk_ = 0; kk_ < 4; ++kk_) {                                       \
        AD[2 * kk_ + 0] = *(const bf16x8*)(wk_ + (kk_ * 2 + 0) * 512 + lane * 8); \
        AD[2 * kk_ + 1] = *(const bf16x8*)(wk_ + (kk_ * 2 + 1) * 512 + lane * 8); \
    }                                                                         \
} while (0)

#define OFF_MFMA(BD, AD) do {                                                 \
    _Pragma("unroll")                                                         \
    for (int kk_ = 0; kk_ < 4; ++kk_) {                                       \
        acc0 = __builtin_amdgcn_mfma_f32_16x16x32_bf16(                       \
                   AD[2 * kk_ + 0], BD[kk_], acc0, 0, 0, 0);                  \
        acc1 = __builtin_amdgcn_mfma_f32_16x16x32_bf16(                       \
                   AD[2 * kk_ + 1], BD[kk_], acc1, 0, 0, 0);                  \
    }                                                                         \
} while (0)

// prefetch tap KN into bank N, then run MFMA on bank C
#define OFF_STEP(KN, BN, AN, BC, AC) do {                                     \
    OFF_LOADA(KN, AN); OFF_LOADB(KN, BN);                                     \
    OFF_MFMA(BC, AC);                                                         \
} while (0)

__global__ __launch_bounds__(256) void off_conv_mfma_kernel(
    const unsigned short* __restrict__ xh,
    const unsigned short* __restrict__ wpo,
    const float* __restrict__ bias,
    unsigned short* __restrict__ offh)
{
    int wgid = blockIdx.x;                   // 512
    int blk  = (wgid & 7) * 64 + (wgid >> 3);
    int b = blk >> 6, oh = blk & 63;
    int tid = threadIdx.x;
    int lane = tid & 63;
    int nt = tid >> 6;
    int nl = lane & 15;
    int kg = lane >> 4;

    f32x4 acc0 = {0.f, 0.f, 0.f, 0.f}, acc1 = {0.f, 0.f, 0.f, 0.f};
    const unsigned short* xb = xh + (size_t)b * HH * WW * CH;

    bf16x8 bA[4], bB[4], aA[8], aB[8];

    OFF_LOADA(0, aA); OFF_LOADB(0, bA);      // tap 0 in flight
    OFF_STEP(1, bB, aB, bA, aA);             // prefetch 1, mfma 0
    OFF_STEP(2, bA, aA, bB, aB);             // prefetch 2, mfma 1
    OFF_STEP(3, bB, aB, bA, aA);
    OFF_STEP(4, bA, aA, bB, aB);
    OFF_STEP(5, bB, aB, bA, aA);
    OFF_STEP(6, bA, aA, bB, aB);
    OFF_STEP(7, bB, aB, bA, aA);
    OFF_STEP(8, bA, aA, bB, aB);             // prefetch 8, mfma 7
    OFF_MFMA(bA, aA);                        // mfma 8

    int ow = nt * 16 + nl;
    #pragma unroll
    for (int r = 0; r < 4; ++r) {
        int co = kg * 4 + r;
        offh[(((size_t)b * OFFC + co) * HH + oh) * WW + ow] = f2bf(acc0[r] + bias[co]);
    }
    if (kg == 0) {
        #pragma unroll
        for (int r = 0; r < 2; ++r) {
            int co = 16 + r;
            offh[(((size_t)b * OFFC + co) * HH + oh) * WW + ow] = f2bf(acc1[r] + bias[co]);
        }
    }
}

// ---------------------------------------------------------------------------
// Deformable conv — PRODUCER/CONSUMER with DEEP PREFETCH (r14, unchanged —
// best measured family: 90.6-90.9 µs total).
// ---------------------------------------------------------------------------
#define P_COORD(K, OW, CW, PTR) do {                                          \
    int ky_ = (K) / 3, kx_ = (K) - ky_ * 3;                                   \
    float dy_ = off_s[2 * (K)][OW];                                           \
    float dx_ = off_s[2 * (K) + 1][OW];                                       \
    float ys_ = (float)(oh - 2 + ky_ * 2) + dy_;                              \
    float xs_ = (float)((OW) - 2 + kx_ * 2) + dx_;                            \
    float y0f_ = floorf(ys_), x0f_ = floorf(xs_);                             \
    float fy_ = ys_ - y0f_, fx_ = xs_ - x0f_;                                 \
    int y0_ = (int)y0f_, x0_ = (int)x0f_;                                     \
    int y1_ = y0_ + 1, x1_ = x0_ + 1;                                         \
    bool vy0_ = (y0_ >= 0) & (y0_ < HH), vy1_ = (y1_ >= 0) & (y1_ < HH);      \
    bool vx0_ = (x0_ >= 0) & (x0_ < WW), vx1_ = (x1_ >= 0) & (x1_ < WW);      \
    int y0c_ = min(max(y0_, 0), HH - 1), y1c_ = min(max(y1_, 0), HH - 1);     \
    int x0c_ = min(max(x0_, 0), WW - 1), x1c_ = min(max(x1_, 0), WW - 1);     \
    CW[0] = (1.f - fy_) * (1.f - fx_) * ((vy0_ && vx0_) ? 1.f : 0.f);         \
    CW[1] = (1.f - fy_) * fx_         * ((vy0_ && vx1_) ? 1.f : 0.f);         \
    CW[2] = fy_ * (1.f - fx_)         * ((vy1_ && vx0_) ? 1.f : 0.f);         \
    CW[3] = fy_ * fx_                 * ((vy1_ && vx1_) ? 1.f : 0.f);         \
    PTR[0] = xb + ((size_t)(y0c_ * WW + x0c_)) * CH + cig * 8;                \
    PTR[1] = xb + ((size_t)(y0c_ * WW + x1c_)) * CH + cig * 8;                \
    PTR[2] = xb + ((size_t)(y1c_ * WW + x0c_)) * CH + cig * 8;                \
    PTR[3] = xb + ((size_t)(y1c_ * WW + x1c_)) * CH + cig * 8;                \
} while (0)

#define P_ISSUE(PTR, LD) do {                                                 \
    _Pragma("unroll")                                                         \
    for (int c_ = 0; c_ < 4; ++c_) {                                          \
        LD[0][c_] = *(const bf16x8*)(PTR[c_]);                                \
        LD[1][c_] = *(const bf16x8*)(PTR[c_] + 64);                           \
    }                                                                         \
} while (0)

#define P_BLEND(OW, CW, LD, BUF) do {                                         \
    int swz_ = ((OW) & 7) << 4;                                               \
    float2 cw0p_ = make_float2(CW[0], CW[0]);                                 \
    float2 cw1p_ = make_float2(CW[1], CW[1]);                                 \
    float2 cw2p_ = make_float2(CW[2], CW[2]);                                 \
    float2 cw3p_ = make_float2(CW[3], CW[3]);                                 \
    _Pragma("unroll")                                                         \
    for (int q_ = 0; q_ < 2; ++q_) {                                          \
        const unsigned int* d0_ = (const unsigned int*)&LD[q_][0];            \
        const unsigned int* d1_ = (const unsigned int*)&LD[q_][1];            \
        const unsigned int* d2_ = (const unsigned int*)&LD[q_][2];            \
        const unsigned int* d3_ = (const unsigned int*)&LD[q_][3];            \
        union { bf16x8 v8; unsigned short u[8]; } wu_;                        \
        _Pragma("unroll")                                                     \
        for (int p_ = 0; p_ < 4; ++p_) {                                      \
            float2 r_ = pk_mul2(cw0p_, bf2f2(d0_[p_]));                       \
            r_ = pk_fma2(cw1p_, bf2f2(d1_[p_]), r_);                          \
            r_ = pk_fma2(cw2p_, bf2f2(d2_[p_]), r_);                          \
            r_ = pk_fma2(cw3p_, bf2f2(d3_[p_]), r_);                          \
            wu_.u[2 * p_]     = f2bf(r_.x);                                   \
            wu_.u[2 * p_ + 1] = f2bf(r_.y);                                   \
        }                                                                     \
        int byte_ = ((OW) * 256 + (q_ * 64 + cig * 8) * 2) ^ swz_;            \
        *(bf16x8*)((char*)sB[BUF] + byte_) = wu_.v8;                          \
    }                                                                         \
} while (0)

#define C_PREF(K, AP) do {                                                    \
    const unsigned short* wk_ = wpk + (size_t)(K) * 16384;                    \
    _Pragma("unroll")                                                         \
    for (int kk_ = 0; kk_ < 4; ++kk_) {                                       \
        AP[kk_ * 2 + 0] = *(const bf16x8*)(wk_ + (size_t)(kk_ * 8 + 2 * cwi)     * 512 + lane * 8); \
        AP[kk_ * 2 + 1] = *(const bf16x8*)(wk_ + (size_t)(kk_ * 8 + 2 * cwi + 1) * 512 + lane * 8); \
    }                                                                         \
} while (0)

__global__ __launch_bounds__(512, 4) void deform_pc_kernel(
    const unsigned short* __restrict__ xh,    // (B,64,64,128) bf16 (sampled)
    const unsigned short* __restrict__ offh,  // (B,18,64,64) bf16
    const unsigned short* __restrict__ wpk,   // packed A frags [9][4kk][8ot][512]
    const float* __restrict__ g, const float* __restrict__ beta,
    const float* __restrict__ m, const float* __restrict__ v,
    const float* __restrict__ residual,       // layer2 only
    unsigned short* __restrict__ out_h,       // layer1: NHWC bf16 out
    float* __restrict__ out_f)                // layer2: NCHW f32 out
{
    __shared__ unsigned short sB[2][64 * 128]; // 32 KB ring [buf][ow][ci] swz
    __shared__ float off_s[OFFC][WW];          // 4.5 KB offsets (f32)
    __shared__ int flg[4];                     // [0,1]=prod_cnt [2,3]=cons_cnt

    int wgid = blockIdx.x;                    // 512
    int blk  = (wgid & 7) * 64 + (wgid >> 3); // XCD n owns batch n
    int b = blk >> 6, oh = blk & 63;
    int tid = threadIdx.x, lane = tid & 63, wv = tid >> 6;

    const unsigned short* xb = xh + (size_t)b * HH * WW * CH;

    // stage offsets + init flags, single barrier (before any loop loads)
    for (int i = tid; i < OFFC * WW; i += 512) {
        int co = i >> 6, owl = i & 63;
        off_s[co][owl] =
            bf2f(offh[(((size_t)b * OFFC + co) * HH + oh) * WW + owl]);
    }
    if (tid < 4) flg[tid] = 0;
    __syncthreads();

    if (wv < 4) {
        // =================== PRODUCER =====================================
        int s_ow = tid >> 3;                  // 0..31 (also serves +32)
        int cig  = tid & 7;                   // 16B chunk id within pixel

        float cwA[4], cwB[4];
        const unsigned short *ptA[4], *ptB[4];
        bf16x8 ldA[2][4], ldB[2][4];

        P_COORD(0, s_ow, cwA, ptA);
        P_COORD(0, s_ow + 32, cwB, ptB);
        P_ISSUE(ptA, ldA);
        P_ISSUE(ptB, ldB);

        for (int k = 0; k < 9; ++k) {
            int buf = k & 1;
            if (k >= 2) {
                int tgt = 4 * (k >> 1);       // consumers done with tap k-2
                while (__hip_atomic_load(&flg[2 + buf], __ATOMIC_ACQUIRE,
                                         __HIP_MEMORY_SCOPE_WORKGROUP) < tgt)
                    __builtin_amdgcn_s_sleep(1);
            }
            P_BLEND(s_ow,      cwA, ldA, buf);
            P_BLEND(s_ow + 32, cwB, ldB, buf);
            asm volatile("s_waitcnt lgkmcnt(0)" ::: "memory");
            if (lane == 0)
                __hip_atomic_fetch_add(&flg[buf], 1, __ATOMIC_RELEASE,
                                       __HIP_MEMORY_SCOPE_WORKGROUP);
            if (k < 8) {
                P_COORD(k + 1, s_ow, cwA, ptA);
                P_COORD(k + 1, s_ow + 32, cwB, ptB);
                P_ISSUE(ptA, ldA);
                P_ISSUE(ptB, ldB);
            }
        }
    } else {
        // =================== CONSUMER =====================================
        int cwi = wv - 4;                     // 0..3: o-tiles {2cwi, 2cwi+1}
        f32x4 acc[2][4];
        #pragma unroll
        for (int a = 0; a < 2; ++a)
            #pragma unroll
            for (int q = 0; q < 4; ++q) acc[a][q] = (f32x4){0.f, 0.f, 0.f, 0.f};

        bf16x8 aP[8];
        C_PREF(0, aP);                        // A frags for tap 0 in flight

        for (int k = 0; k < 9; ++k) {
            int buf = k & 1;
            int tgt = 4 * ((k >> 1) + 1);     // producers done with tap k
            while (__hip_atomic_load(&flg[buf], __ATOMIC_ACQUIRE,
                                     __HIP_MEMORY_SCOPE_WORKGROUP) < tgt)
                __builtin_amdgcn_s_sleep(1);

            __builtin_amdgcn_s_setprio(1);
            #pragma unroll
            for (int kk = 0; kk < 4; ++kk) {
                #pragma unroll
                for (int owt = 0; owt < 4; ++owt) {
                    int owl = owt * 16 + (lane & 15);
                    int rbyte = (owl * 256 + (kk * 32 + (lane >> 4) * 8) * 2)
                                ^ ((owl & 7) << 4);
                    bf16x8 bfv = *(const bf16x8*)((const char*)sB[buf] + rbyte);
                    acc[0][owt] = __builtin_amdgcn_mfma_f32_16x16x32_bf16(
                                      aP[kk * 2 + 0], bfv, acc[0][owt], 0, 0, 0);
                    acc[1][owt] = __builtin_amdgcn_mfma_f32_16x16x32_bf16(
                                      aP[kk * 2 + 1], bfv, acc[1][owt], 0, 0, 0);
                }
            }
            __builtin_amdgcn_s_setprio(0);
            asm volatile("s_waitcnt lgkmcnt(0)" ::: "memory");
            if (lane == 0)
                __hip_atomic_fetch_add(&flg[2 + buf], 1, __ATOMIC_RELEASE,
                                       __HIP_MEMORY_SCOPE_WORKGROUP);
            if (k < 8) C_PREF(k + 1, aP);
        }

        // ---- epilogue (consumers hold all 128 o across 4 waves) --------
        #pragma unroll
        for (int otl = 0; otl < 2; ++otl) {
            int ob = (2 * cwi + otl) * 16 + (lane >> 4) * 4;
            float inv[4], sh[4];
            #pragma unroll
            for (int r = 0; r < 4; ++r) {
                int o = ob + r;
                float iv = g[o] / sqrtf(v[o] + 1e-5f);
                inv[r] = iv; sh[r] = beta[o] - m[o] * iv;
            }
            if (out_h != nullptr) {
                #pragma unroll
                for (int owt = 0; owt < 4; ++owt) {
                    int ow = owt * 16 + (lane & 15);
                    union { bf16x4 v4; unsigned short u[4]; } pk;
                    #pragma unroll
                    for (int r = 0; r < 4; ++r) {
                        float val = acc[otl][owt][r] * inv[r] + sh[r];
                        pk.u[r] = f2bf(fmaxf(val, 0.f));
                    }
                    *(bf16x4*)(out_h + ((size_t)(b * HH + oh) * WW + ow) * CH + ob) = pk.v4;
                }
            } else {
                #pragma unroll
                for (int r = 0; r < 4; ++r) {
                    int o = ob + r;
                    #pragma unroll
                    for (int owt = 0; owt < 4; ++owt) {
                        int ow = owt * 16 + (lane & 15);
                        size_t idx = (((size_t)b * CH + o) * HH + oh) * WW + ow;
                        float val = acc[otl][owt][r] * inv[r] + sh[r] + residual[idx];
                        out_f[idx] = fmaxf(val, 0.f);
                    }
                }
            }
        }
    }
}

// ---------------------------------------------------------------------------
extern "C" void kernel_launch(void* const* d_in, const int* in_sizes, int n_in,
                              void* d_out, int out_size, void* d_ws, size_t ws_size,
                              hipStream_t stream)
{
    const float* x      = (const float*)d_in[0];
    const float* w_off1 = (const float*)d_in[1];
    const float* b_off1 = (const float*)d_in[2];
    const float* w_dc1  = (const float*)d_in[3];
    const float* g1     = (const float*)d_in[4];
    const float* beta1  = (const float*)d_in[5];
    const float* m1     = (const float*)d_in[6];
    const float* v1     = (const float*)d_in[7];
    const float* w_off2 = (const float*)d_in[8];
    const float* b_off2 = (const float*)d_in[9];
    const float* w_dc2  = (const float*)d_in[10];
    const float* g2     = (const float*)d_in[11];
    const float* beta2  = (const float*)d_in[12];
    const float* m2     = (const float*)d_in[13];
    const float* v2     = (const float*)d_in[14];
    float* out = (float*)d_out;

    char* ws = (char*)d_ws;
    unsigned short* xh    = (unsigned short*)ws;                  // 8,388,608 B
    unsigned short* out1h = (unsigned short*)(ws + 8388608);      // 8,388,608 B
    unsigned short* offh  = (unsigned short*)(ws + 16777216);     // 1,179,648 B
    unsigned short* wpk1  = (unsigned short*)(ws + 17956864);     //   294,912 B
    unsigned short* wpk2  = (unsigned short*)(ws + 18251776);     //   294,912 B
    unsigned short* wpo1  = (unsigned short*)(ws + 18546688);     //    73,728 B
    unsigned short* wpo2  = (unsigned short*)(ws + 18620416);     //    73,728 B

    prep_kernel<<<1952, 256, 0, stream>>>(x, xh, w_dc1, w_dc2, w_off1, w_off2,
                                          wpk1, wpk2, wpo1, wpo2);

    // Layer 1
    off_conv_mfma_kernel<<<512, 256, 0, stream>>>(xh, wpo1, b_off1, offh);
    deform_pc_kernel<<<512, 512, 0, stream>>>(xh, offh, wpk1,
                                              g1, beta1, m1, v1,
                                              nullptr, out1h, nullptr);
    // Layer 2
    off_conv_mfma_kernel<<<512, 256, 0, stream>>>(out1h, wpo2, b_off2, offh);
    deform_pc_kernel<<<512, 512, 0, stream>>>(out1h, offh, wpk2,
                                              g2, beta2, m2, v2,
                                              x, nullptr, out);
}